// Round 6
// baseline (290.179 us; speedup 1.0000x reference)
//
#include <hip/hip_runtime.h>

#define B_DIM 8
#define C_DIM 256
#define I_DIM 128
#define N_DIM 4096
#define R_DIM 64

typedef unsigned short u16;
typedef unsigned int u32;
typedef __attribute__((ext_vector_type(8))) __bf16 bf16x8;
typedef __attribute__((ext_vector_type(4))) float f32x4;
typedef __attribute__((ext_vector_type(16))) float f32x16;

union BF8 { u32 u[4]; bf16x8 v; };

__device__ __forceinline__ u16 f2bf(float f) {
    union { float f; u32 u; } v; v.f = f;
    u32 r = v.u + 0x7FFFu + ((v.u >> 16) & 1u);
    return (u16)(r >> 16);
}
__device__ __forceinline__ float bf2f(u16 h) {
    union { u32 u; float f; } v; v.u = (u32)h << 16; return v.f;
}
__device__ __forceinline__ u32 pk2(float a, float b) {
    return (u32)f2bf(a) | ((u32)f2bf(b) << 16);
}
// truncating bf16 pack: [b.hi16 | a.hi16] in ONE v_perm_b32
__device__ __forceinline__ u32 pk2t(float a, float b) {
    union { float f; u32 u; } ua, ub; ua.f = a; ub.f = b;
    return __builtin_amdgcn_perm(ub.u, ua.u, 0x07060302u);
}
__device__ __forceinline__ void async16(const u16* g, u16* l) {
    __builtin_amdgcn_global_load_lds((const __attribute__((address_space(1))) void*)g,
                                     (__attribute__((address_space(3))) void*)l, 16, 0, 0);
}

// log2(e)/sqrt(128), folded into theta at projection time
#define TH_SCALE 0.1275204890136f

// ---- workspace layout (bytes) ----
static constexpr size_t OFF_BNSUM = 0;
static constexpr size_t OFF_BNSQ  = 1024;
static constexpr size_t OFF_POOL  = 2048;
static constexpr size_t OFF_CHW   = 10240;
static constexpr size_t OFF_W3    = 18432;                  // 3*128*256 bf16
static constexpr size_t OFF_OWB   = 215040;                 // 256*128 bf16
static constexpr size_t OFF_AO0   = 280576;                 // [B,N,I] bf16 partial 0
static constexpr size_t OFF_AO1   = OFF_AO0 + 8388608;      // partial 1
static constexpr size_t OFF_THETA = OFF_AO1 + 8388608;      // [B,N,I] bf16 (pre-scaled)
static constexpr size_t OFF_PHIT  = OFF_THETA + 8388608;
static constexpr size_t OFF_GT    = OFF_PHIT + 8388608;     // [B,I,N] bf16
static constexpr size_t OFF_L0    = OFF_GT + 8388608;       // [B,N] f32
static constexpr size_t OFF_L1    = OFF_L0 + 131072;
static constexpr size_t OFF_OUT2  = OFF_L1 + 131072;        // [B,C,N] bf16

// ---- 1: weight convert + zero accumulators ----
__global__ void prep_kernel(const float* __restrict__ tw, const float* __restrict__ pw,
                            const float* __restrict__ gw, const float* __restrict__ ow,
                            u16* __restrict__ w3, u16* __restrict__ owb,
                            float* __restrict__ bnzero, float* __restrict__ pooled) {
    int idx = blockIdx.x * 256 + threadIdx.x;
    if (idx < 512) bnzero[idx] = 0.f;
    if (idx < 2048) pooled[idx] = 0.f;
    if (idx < 3 * 32768) {
        const float* src = idx < 32768 ? tw : (idx < 65536 ? pw : gw);
        w3[idx] = f2bf(src[idx & 32767]);
    }
    if (idx < 32768) owb[idx] = f2bf(ow[idx]);
}

// ---- 3: SE MLP (runs after qkv, which accumulates pooled sums) ----
__global__ void se_kernel(const float* __restrict__ pooled,
                          const float* __restrict__ fc1w, const float* __restrict__ fc1b,
                          const float* __restrict__ fc2w, const float* __restrict__ fc2b,
                          float* __restrict__ chw) {
    int b = blockIdx.x, t = threadIdx.x;
    __shared__ float sp[C_DIM], sh[R_DIM];
    sp[t] = pooled[b * C_DIM + t] * (1.f / N_DIM);
    __syncthreads();
    if (t < R_DIM) {
        float a = fc1b[t];
        for (int c = 0; c < C_DIM; ++c) a += sp[c] * fc1w[t * C_DIM + c];
        sh[t] = a > 0.f ? a : 0.f;
    }
    __syncthreads();
    float a = fc2b[t];
    for (int j = 0; j < R_DIM; ++j) a += sh[j] * fc2w[t * R_DIM + j];
    chw[b * C_DIM + t] = 1.f / (1.f + __builtin_amdgcn_exp2f(-a * 1.44269504089f));
}

// ---- 4: fused QKV projection (direct from x, 32x32x16 MFMA) + SE pooling ----
__global__ __launch_bounds__(256) void qkv_kernel(const float* __restrict__ x,
                                                  const u16* __restrict__ w3,
                                                  u16* __restrict__ theta,
                                                  u16* __restrict__ phiT,
                                                  u16* __restrict__ gT,
                                                  float* __restrict__ pooled) {
    const int bid = blockIdx.x;
    const int b = bid & 7, nt = bid >> 3;
    const int n0 = nt * 64;
    const int t = threadIdx.x, lane = t & 63, w = t >> 6;
    const int cl = lane & 31, h = lane >> 5;

    __shared__ u16 As[64 * 256];   // [n][c] bf16, 16B-granule swizzled ^(n&7)
    __shared__ u16 Ep[128 * 72];   // epilogue buffer

    {   // stage x[b, :, n0:n0+64] -> As (transposed to [n][c]); fused SE pooling
        const float* xb = x + ((size_t)b * C_DIM) * N_DIM + n0;
        for (int it = 0; it < 16; ++it) {
            int id = it * 256 + t;
            int c = id >> 4, l16 = id & 15;
            float4 v = *(const float4*)(xb + (size_t)c * N_DIM + l16 * 4);
            int g = c >> 3, co = c & 7;
            float vv[4] = {v.x, v.y, v.z, v.w};
            #pragma unroll
            for (int k = 0; k < 4; ++k) {
                int n = l16 * 4 + k;
                As[n * 256 + ((g ^ (n & 7)) << 3) + co] = f2bf(vv[k]);
            }
            float s = (v.x + v.y) + (v.z + v.w);
            s += __shfl_xor(s, 1); s += __shfl_xor(s, 2);
            s += __shfl_xor(s, 4); s += __shfl_xor(s, 8);
            if ((t & 15) == 0) atomicAdd(&pooled[b * C_DIM + c], s);
        }
    }
    __syncthreads();

    const int mt = w & 1;    // n-tile
    const int ip = w >> 1;   // i-pair
    bf16x8 afr[16];
    #pragma unroll
    for (int ks = 0; ks < 16; ++ks) {
        int r = mt * 32 + cl;
        int g = 2 * ks + h;
        afr[ks] = *(const bf16x8*)&As[r * 256 + ((g ^ (r & 7)) << 3)];
    }

    for (int z = 0; z < 3; ++z) {
        const u16* wz = w3 + z * (I_DIM * C_DIM);
        f32x16 acc[2] = {};
        #pragma unroll
        for (int ks = 0; ks < 16; ++ks) {
            #pragma unroll
            for (int f = 0; f < 2; ++f) {
                int irow = (2 * ip + f) * 32 + cl;
                bf16x8 bfr = *(const bf16x8*)(wz + (size_t)irow * C_DIM + ks * 16 + h * 8);
                acc[f] = __builtin_amdgcn_mfma_f32_32x32x16_bf16(afr[ks], bfr, acc[f], 0, 0, 0);
            }
        }
        if (z < 2) {
            float sc = (z == 0) ? TH_SCALE : 1.0f;
            // Ep as [n64][i 136pad]
            #pragma unroll
            for (int f = 0; f < 2; ++f) {
                int i = (2 * ip + f) * 32 + cl;
                #pragma unroll
                for (int r2 = 0; r2 < 4; ++r2)
                    #pragma unroll
                    for (int e = 0; e < 4; ++e) {
                        int n = mt * 32 + 8 * r2 + 4 * h + e;
                        Ep[n * 136 + i] = f2bf(acc[f][4 * r2 + e] * sc);
                    }
            }
            __syncthreads();
            u16* dst = (z == 0) ? theta : phiT;
            #pragma unroll
            for (int it = 0; it < 4; ++it) {
                int id = it * 256 + t;
                int n = id >> 4, l16 = id & 15;
                f32x4 vv = *(const f32x4*)&Ep[n * 136 + l16 * 8];
                *(f32x4*)(dst + ((size_t)(b * N_DIM) + n0 + n) * I_DIM + l16 * 8) = vv;
            }
            __syncthreads();
        } else {
            // Ep as [i128][n 72pad]
            #pragma unroll
            for (int f = 0; f < 2; ++f) {
                int i = (2 * ip + f) * 32 + cl;
                #pragma unroll
                for (int r2 = 0; r2 < 4; ++r2) {
                    u32 lo = pk2(acc[f][4 * r2 + 0], acc[f][4 * r2 + 1]);
                    u32 hi = pk2(acc[f][4 * r2 + 2], acc[f][4 * r2 + 3]);
                    int nb = mt * 32 + 8 * r2 + 4 * h;
                    *(u32*)&Ep[i * 72 + nb] = lo;
                    *(u32*)&Ep[i * 72 + nb + 2] = hi;
                }
            }
            __syncthreads();
            #pragma unroll
            for (int it = 0; it < 4; ++it) {
                int id = it * 256 + t;
                int i = id >> 3, l8 = id & 7;
                f32x4 vv = *(const f32x4*)&Ep[i * 72 + l8 * 8];
                *(f32x4*)(gT + ((size_t)(b * I_DIM) + i) * N_DIM + n0 + l8 * 8) = vv;
            }
        }
    }
}

// ---- 5: flash attention, 32x32 MFMA, q=64/wave (qtile=256/block), dbuf K/V ----
// grid 256 = 1 block/CU; MFMA-bound: kf/vf LDS frags reused across both q-tiles.
__global__ __launch_bounds__(256) void attn_kernel(const u16* __restrict__ theta,
                                                   const u16* __restrict__ phiT,
                                                   const u16* __restrict__ gT,
                                                   u16* __restrict__ ao0, u16* __restrict__ ao1,
                                                   float* __restrict__ l0, float* __restrict__ l1) {
    const int bid = blockIdx.x;
    const int b = bid & 7, mh = (bid >> 3) & 1, qt = bid >> 4;
    const int t = threadIdx.x, lane = t & 63, w = t >> 6;
    const int cl = lane & 31, h = lane >> 5;
    const int qw = qt * 256 + w * 64;    // wave q-base (64 queries/wave)

    __shared__ u16 SM[32768];            // 64KB: K0 V0 | K1 V1 (reused for epilogue)
    __shared__ float lex[4][64];

    // Q B-frags for 2 q-col-tiles: B[k=i][n=q], q = qi*32+cl, k = ks*16+h*8
    bf16x8 qf[2][8];
    #pragma unroll
    for (int qi = 0; qi < 2; ++qi) {
        const u16* qp = theta + ((size_t)(b * N_DIM) + qw + qi * 32 + cl) * I_DIM + h * 8;
        #pragma unroll
        for (int ks = 0; ks < 8; ++ks) qf[qi][ks] = *(const bf16x8*)(qp + ks * 16);
    }

    const u16* kbase = phiT + (size_t)b * N_DIM * I_DIM + (size_t)(mh * 2048) * I_DIM;
    const u16* vbase = gT + (size_t)b * I_DIM * N_DIM + mh * 2048;
    const u16* kptr[4]; const u16* vptr[4];
    #pragma unroll
    for (int it = 0; it < 4; ++it) {
        int gi = (w * 4 + it) * 64 + lane;
        int kr = gi >> 4, kg = gi & 15;
        kptr[it] = kbase + (size_t)kr * I_DIM + ((kg ^ (kr & 7)) << 3);
        int vr = gi >> 3, vg = gi & 7;
        vptr[it] = vbase + (size_t)vr * N_DIM + ((vg ^ (vr & 7)) << 3);
    }

    auto issue = [&](int p) {
        u16* Kd = SM + p * 16384;
        u16* Vd = SM + p * 16384 + 8192;
        #pragma unroll
        for (int it = 0; it < 4; ++it) { async16(kptr[it], Kd + (w * 4 + it) * 512); kptr[it] += 64 * I_DIM; }
        #pragma unroll
        for (int it = 0; it < 4; ++it) { async16(vptr[it], Vd + (w * 4 + it) * 512); vptr[it] += 64; }
    };

    float lsum[2] = {0.f, 0.f};
    f32x16 O[2][4] = {};

    issue(0);   // chunk 0 -> buf 0

    for (int mc = 0; mc < 32; ++mc) {
        const int p = mc & 1;
        // (A) all waves done computing chunk mc-1 -> buf 1-p free to overwrite
        __asm__ volatile("s_barrier" ::: "memory");
        if (mc < 31) {
            issue(1 - p);   // prefetch chunk mc+1; stays in flight across barrier B
            __asm__ volatile("s_waitcnt vmcnt(8)" ::: "memory");
        } else {
            __asm__ volatile("s_waitcnt vmcnt(0)" ::: "memory");
        }
        // (B) all waves' chunk-mc loads retired -> buf p fully populated
        __asm__ volatile("s_barrier" ::: "memory");

        const u16* Ks = SM + p * 16384;
        const u16* Vs = SM + p * 16384 + 8192;

        #pragma unroll
        for (int mt2 = 0; mt2 < 2; ++mt2) {
            // K A-frags for this m-half, reused across both q-tiles
            bf16x8 kf[8];
            #pragma unroll
            for (int ks = 0; ks < 8; ++ks) {
                int r = mt2 * 32 + cl;
                kf[ks] = *(const bf16x8*)&Ks[r * 128 + (((2 * ks + h) ^ (r & 7)) << 3)];
            }
            // S^T = K Q^T; theta pre-scaled so P = exp2(S)
            u32 pkq[2][4][2];
            #pragma unroll
            for (int qi = 0; qi < 2; ++qi) {
                f32x16 S = {};
                #pragma unroll
                for (int ks = 0; ks < 8; ++ks)
                    S = __builtin_amdgcn_mfma_f32_32x32x16_bf16(kf[ks], qf[qi][ks], S, 0, 0, 0);
                #pragma unroll
                for (int r2 = 0; r2 < 4; ++r2) {
                    float p0 = __builtin_amdgcn_exp2f(S[4 * r2 + 0]);
                    float p1 = __builtin_amdgcn_exp2f(S[4 * r2 + 1]);
                    float p2 = __builtin_amdgcn_exp2f(S[4 * r2 + 2]);
                    float p3 = __builtin_amdgcn_exp2f(S[4 * r2 + 3]);
                    lsum[qi] += (p0 + p1) + (p2 + p3);
                    pkq[qi][r2][0] = pk2t(p0, p1);
                    pkq[qi][r2][1] = pk2t(p2, p3);
                }
            }
            // O += P V for this m-half's two granule-pairs; vf reused across q-tiles
            #pragma unroll
            for (int l = 0; l < 2; ++l) {
                const int gks = 2 * mt2 + l;
                BF8 A[2];
                #pragma unroll
                for (int qi = 0; qi < 2; ++qi) {
                    u32 a0 = pkq[qi][2 * l][0], a1 = pkq[qi][2 * l][1];
                    u32 b0 = pkq[qi][2 * l + 1][0], b1 = pkq[qi][2 * l + 1][1];
                    bool hb = (h != 0);
                    u32 own0 = hb ? b0 : a0, own1 = hb ? b1 : a1;
                    u32 xf0 = hb ? a0 : b0, xf1 = hb ? a1 : b1;
                    u32 rc0 = (u32)__shfl_xor((int)xf0, 32);
                    u32 rc1 = (u32)__shfl_xor((int)xf1, 32);
                    A[qi].u[0] = hb ? rc0 : own0;
                    A[qi].u[1] = hb ? rc1 : own1;
                    A[qi].u[2] = hb ? own0 : rc0;
                    A[qi].u[3] = hb ? own1 : rc1;
                }
                #pragma unroll
                for (int f = 0; f < 4; ++f) {
                    int ir = f * 32 + cl;
                    bf16x8 vf = *(const bf16x8*)&Vs[ir * 64 + (((2 * gks + h) ^ (ir & 7)) << 3)];
                    O[0][f] = __builtin_amdgcn_mfma_f32_32x32x16_bf16(A[0].v, vf, O[0][f], 0, 0, 0);
                    O[1][f] = __builtin_amdgcn_mfma_f32_32x32x16_bf16(A[1].v, vf, O[1][f], 0, 0, 0);
                }
            }
        }
    }

    // l totals (column q sums split across halves)
    lsum[0] += __shfl_xor(lsum[0], 32);
    lsum[1] += __shfl_xor(lsum[1], 32);
    if (h == 0) { lex[w][cl] = lsum[0]; lex[w][32 + cl] = lsum[1]; }
    __syncthreads();   // lex visible + all waves done with buf1 -> SM reusable

    float linv[2][16];
    #pragma unroll
    for (int qi = 0; qi < 2; ++qi) {
        #pragma unroll
        for (int r2 = 0; r2 < 4; ++r2) {
            f32x4 lv = *(const f32x4*)&lex[w][qi * 32 + 8 * r2 + 4 * h];
            #pragma unroll
            for (int e = 0; e < 4; ++e) linv[qi][4 * r2 + e] = 1.f / lv[e];
        }
    }

    u16* aop = (mh == 0) ? ao0 : ao1;
    float* lp = (mh == 0) ? l0 : l1;
    if (h == 0) {
        lp[(size_t)b * N_DIM + qw + cl] = lsum[0];
        lp[(size_t)b * N_DIM + qw + 32 + cl] = lsum[1];
    }

    u16* ep = SM + w * 8192;   // [q64][i128] per wave, 16KB each
    #pragma unroll
    for (int qi = 0; qi < 2; ++qi)
        #pragma unroll
        for (int f = 0; f < 4; ++f)
            #pragma unroll
            for (int r2 = 0; r2 < 4; ++r2)
                #pragma unroll
                for (int e = 0; e < 4; ++e) {
                    int q = qi * 32 + 8 * r2 + 4 * h + e;
                    ep[q * 128 + f * 32 + cl] = f2bf(O[qi][f][4 * r2 + e] * linv[qi][4 * r2 + e]);
                }
    __asm__ volatile("s_waitcnt lgkmcnt(0)" ::: "memory");
    #pragma unroll
    for (int it = 0; it < 16; ++it) {
        int id = it * 64 + lane;
        int q = id >> 4, l16 = id & 15;
        f32x4 vv = *(const f32x4*)&ep[q * 128 + l16 * 8];
        *(f32x4*)(aop + ((size_t)(b * N_DIM) + qw + q) * I_DIM + l16 * 8) = vv;
    }
}

// ---- 6: out projection + partial combine + BN stats ----
__global__ __launch_bounds__(256) void oproj_kernel(const u16* __restrict__ ao0,
                                                    const u16* __restrict__ ao1,
                                                    const float* __restrict__ l0,
                                                    const float* __restrict__ l1,
                                                    const u16* __restrict__ owb,
                                                    u16* __restrict__ out2,
                                                    float* __restrict__ bnsum,
                                                    float* __restrict__ bnsumsq) {
    const int bid = blockIdx.x;
    const int b = bid & 7, nt = bid >> 3;
    const int n0 = nt * 64;
    const int t = threadIdx.x, lane = t & 63, w = t >> 6;
    const int cl = lane & 31, h = lane >> 5;

    __shared__ u16 Ep[256 * 72];   // [c][n 72pad]
    __shared__ float lsum[C_DIM], lsq[C_DIM];
    lsum[t] = 0.f; lsq[t] = 0.f;
    __syncthreads();

    const int mt = w & 1;
    const int nn = n0 + mt * 32 + cl;
    float w0, w1;
    {
        float la = l0[(size_t)b * N_DIM + nn], lb = l1[(size_t)b * N_DIM + nn];
        float inv = 1.f / (la + lb);
        w0 = la * inv; w1 = lb * inv;
    }
    bf16x8 afr[8];
    {
        const u16* p0 = ao0 + ((size_t)(b * N_DIM) + nn) * I_DIM + h * 8;
        const u16* p1 = ao1 + ((size_t)(b * N_DIM) + nn) * I_DIM + h * 8;
        #pragma unroll
        for (int ks = 0; ks < 8; ++ks) {
            bf16x8 x0 = *(const bf16x8*)(p0 + ks * 16);
            bf16x8 x1 = *(const bf16x8*)(p1 + ks * 16);
            const u16* u0 = (const u16*)&x0;
            const u16* u1 = (const u16*)&x1;
            float c0 = w0 * bf2f(u0[0]) + w1 * bf2f(u1[0]);
            float c1 = w0 * bf2f(u0[1]) + w1 * bf2f(u1[1]);
            float c2 = w0 * bf2f(u0[2]) + w1 * bf2f(u1[2]);
            float c3 = w0 * bf2f(u0[3]) + w1 * bf2f(u1[3]);
            float c4 = w0 * bf2f(u0[4]) + w1 * bf2f(u1[4]);
            float c5 = w0 * bf2f(u0[5]) + w1 * bf2f(u1[5]);
            float c6 = w0 * bf2f(u0[6]) + w1 * bf2f(u1[6]);
            float c7 = w0 * bf2f(u0[7]) + w1 * bf2f(u1[7]);
            BF8 r;
            r.u[0] = pk2(c0, c1); r.u[1] = pk2(c2, c3);
            r.u[2] = pk2(c4, c5); r.u[3] = pk2(c6, c7);
            afr[ks] = r.v;
        }
    }

    f32x16 D[4] = {};
    #pragma unroll
    for (int ks = 0; ks < 8; ++ks) {
        #pragma unroll
        for (int j = 0; j < 4; ++j) {
            int cr = ((w >> 1) * 4 + j) * 32 + cl;
            bf16x8 bfr = *(const bf16x8*)(owb + (size_t)cr * I_DIM + ks * 16 + h * 8);
            D[j] = __builtin_amdgcn_mfma_f32_32x32x16_bf16(afr[ks], bfr, D[j], 0, 0, 0);
        }
    }

    #pragma unroll
    for (int j = 0; j < 4; ++j) {
        int c = ((w >> 1) * 4 + j) * 32 + cl;
        float s1 = 0.f, s2 = 0.f;
        #pragma unroll
        for (int r2 = 0; r2 < 4; ++r2) {
            float v0 = D[j][4 * r2 + 0], v1 = D[j][4 * r2 + 1];
            float v2 = D[j][4 * r2 + 2], v3 = D[j][4 * r2 + 3];
            s1 += (v0 + v1) + (v2 + v3);
            s2 += (v0 * v0 + v1 * v1) + (v2 * v2 + v3 * v3);
            int nb = mt * 32 + 8 * r2 + 4 * h;
            *(u32*)&Ep[c * 72 + nb] = pk2(v0, v1);
            *(u32*)&Ep[c * 72 + nb + 2] = pk2(v2, v3);
        }
        atomicAdd(&lsum[c], s1);
        atomicAdd(&lsq[c], s2);
    }
    __syncthreads();
    #pragma unroll
    for (int it = 0; it < 8; ++it) {
        int id = it * 256 + t;
        int c = id >> 3, l8 = id & 7;
        f32x4 vv = *(const f32x4*)&Ep[c * 72 + l8 * 8];
        *(f32x4*)(out2 + ((size_t)(b * C_DIM) + c) * N_DIM + n0 + l8 * 8) = vv;
    }
    atomicAdd(&bnsum[t], lsum[t]);
    atomicAdd(&bnsumsq[t], lsq[t]);
}

// ---- 7: BN normalize + SE scale + residual ----
__global__ void final_kernel(const float* __restrict__ x, const u16* __restrict__ out2,
                             const float* __restrict__ bnsum, const float* __restrict__ bnsumsq,
                             const float* __restrict__ gamma, const float* __restrict__ beta,
                             const float* __restrict__ chw, float* __restrict__ out) {
    int idx = blockIdx.x * 256 + threadIdx.x;
    int e = idx * 4;
    int b = e >> 20;
    int c = (e >> 12) & 255;
    float mean = bnsum[c] * (1.f / 32768.f);
    float var = bnsumsq[c] * (1.f / 32768.f) - mean * mean;
    float sc = gamma[c] * rsqrtf(var + 1e-5f);
    float sh = beta[c] - mean * sc;
    float cw = chw[b * C_DIM + c];
    ushort4 o16 = ((const ushort4*)out2)[idx];
    float4 xv = ((const float4*)x)[idx];
    float4 res;
    res.x = xv.x + (bf2f(o16.x) * sc + sh) * cw;
    res.y = xv.y + (bf2f(o16.y) * sc + sh) * cw;
    res.z = xv.z + (bf2f(o16.z) * sc + sh) * cw;
    res.w = xv.w + (bf2f(o16.w) * sc + sh) * cw;
    ((float4*)out)[idx] = res;
}

extern "C" void kernel_launch(void* const* d_in, const int* in_sizes, int n_in,
                              void* d_out, int out_size, void* d_ws, size_t ws_size,
                              hipStream_t stream) {
    const float* x   = (const float*)d_in[0];
    const float* tw  = (const float*)d_in[1];
    const float* pw  = (const float*)d_in[2];
    const float* gw  = (const float*)d_in[3];
    const float* ow  = (const float*)d_in[4];
    const float* gam = (const float*)d_in[5];
    const float* bet = (const float*)d_in[6];
    const float* f1w = (const float*)d_in[7];
    const float* f1b = (const float*)d_in[8];
    const float* f2w = (const float*)d_in[9];
    const float* f2b = (const float*)d_in[10];
    float* out = (float*)d_out;

    char* ws = (char*)d_ws;
    float* bnsum   = (float*)(ws + OFF_BNSUM);
    float* bnsumsq = (float*)(ws + OFF_BNSQ);
    float* pooled  = (float*)(ws + OFF_POOL);
    float* chw     = (float*)(ws + OFF_CHW);
    u16*   w3      = (u16*)(ws + OFF_W3);
    u16*   owb     = (u16*)(ws + OFF_OWB);
    u16*   ao0     = (u16*)(ws + OFF_AO0);
    u16*   ao1     = (u16*)(ws + OFF_AO1);
    u16*   theta   = (u16*)(ws + OFF_THETA);
    u16*   phiT    = (u16*)(ws + OFF_PHIT);
    u16*   gT      = (u16*)(ws + OFF_GT);
    float* l0      = (float*)(ws + OFF_L0);
    float* l1      = (float*)(ws + OFF_L1);
    u16*   out2    = (u16*)(ws + OFF_OUT2);

    prep_kernel<<<384, 256, 0, stream>>>(tw, pw, gw, ow, w3, owb, bnsum, pooled);
    qkv_kernel<<<512, 256, 0, stream>>>(x, w3, theta, phiT, gT, pooled);
    se_kernel<<<B_DIM, 256, 0, stream>>>(pooled, f1w, f1b, f2w, f2b, chw);
    attn_kernel<<<256, 256, 0, stream>>>(theta, phiT, gT, ao0, ao1, l0, l1);
    oproj_kernel<<<512, 256, 0, stream>>>(ao0, ao1, l0, l1, owb, out2, bnsum, bnsumsq);
    final_kernel<<<8192, 256, 0, stream>>>(x, out2, bnsum, bnsumsq, gam, bet, chw, out);
}

// Round 7
// 275.170 us; speedup vs baseline: 1.0545x; 1.0545x over previous
//
#include <hip/hip_runtime.h>

#define B_DIM 8
#define C_DIM 256
#define I_DIM 128
#define N_DIM 4096
#define R_DIM 64

typedef unsigned short u16;
typedef unsigned int u32;
typedef __attribute__((ext_vector_type(8))) __bf16 bf16x8;
typedef __attribute__((ext_vector_type(4))) float f32x4;
typedef __attribute__((ext_vector_type(16))) float f32x16;

union BF8 { u32 u[4]; bf16x8 v; };

__device__ __forceinline__ u16 f2bf(float f) {
    union { float f; u32 u; } v; v.f = f;
    u32 r = v.u + 0x7FFFu + ((v.u >> 16) & 1u);
    return (u16)(r >> 16);
}
__device__ __forceinline__ float bf2f(u16 h) {
    union { u32 u; float f; } v; v.u = (u32)h << 16; return v.f;
}
__device__ __forceinline__ u32 pk2(float a, float b) {
    return (u32)f2bf(a) | ((u32)f2bf(b) << 16);
}
// truncating bf16 pack: [b.hi16 | a.hi16] in ONE v_perm_b32
__device__ __forceinline__ u32 pk2t(float a, float b) {
    union { float f; u32 u; } ua, ub; ua.f = a; ub.f = b;
    return __builtin_amdgcn_perm(ub.u, ua.u, 0x07060302u);
}
__device__ __forceinline__ void async16(const u16* g, u16* l) {
    __builtin_amdgcn_global_load_lds((const __attribute__((address_space(1))) void*)g,
                                     (__attribute__((address_space(3))) void*)l, 16, 0, 0);
}

// log2(e)/sqrt(128), folded into theta at projection time
#define TH_SCALE 0.1275204890136f

// ---- workspace layout (bytes) ----
static constexpr size_t OFF_BNSUM = 0;
static constexpr size_t OFF_BNSQ  = 1024;
static constexpr size_t OFF_POOL  = 2048;
static constexpr size_t OFF_CHW   = 10240;
static constexpr size_t OFF_W3    = 18432;                  // 3*128*256 bf16
static constexpr size_t OFF_OWB   = 215040;                 // 256*128 bf16
static constexpr size_t OFF_AO0   = 280576;                 // [B,N,I] bf16 partial 0 (raw O)
static constexpr size_t OFF_AO1   = OFF_AO0 + 8388608;      // partial 1
static constexpr size_t OFF_THETA = OFF_AO1 + 8388608;      // [B,N,I] bf16 (pre-scaled)
static constexpr size_t OFF_PHIT  = OFF_THETA + 8388608;
static constexpr size_t OFF_GT    = OFF_PHIT + 8388608;     // [B,I,N] bf16
static constexpr size_t OFF_L0    = OFF_GT + 8388608;       // [B,N] f32
static constexpr size_t OFF_L1    = OFF_L0 + 131072;
static constexpr size_t OFF_OUT2  = OFF_L1 + 131072;        // [B,C,N] bf16

// ---- 1: weight convert + zero accumulators ----
__global__ void prep_kernel(const float* __restrict__ tw, const float* __restrict__ pw,
                            const float* __restrict__ gw, const float* __restrict__ ow,
                            u16* __restrict__ w3, u16* __restrict__ owb,
                            float* __restrict__ bnzero, float* __restrict__ pooled) {
    int idx = blockIdx.x * 256 + threadIdx.x;
    if (idx < 512) bnzero[idx] = 0.f;
    if (idx < 2048) pooled[idx] = 0.f;
    if (idx < 3 * 32768) {
        const float* src = idx < 32768 ? tw : (idx < 65536 ? pw : gw);
        w3[idx] = f2bf(src[idx & 32767]);
    }
    if (idx < 32768) owb[idx] = f2bf(ow[idx]);
}

// ---- 3: SE MLP (runs after qkv, which accumulates pooled sums) ----
__global__ void se_kernel(const float* __restrict__ pooled,
                          const float* __restrict__ fc1w, const float* __restrict__ fc1b,
                          const float* __restrict__ fc2w, const float* __restrict__ fc2b,
                          float* __restrict__ chw) {
    int b = blockIdx.x, t = threadIdx.x;
    __shared__ float sp[C_DIM], sh[R_DIM];
    sp[t] = pooled[b * C_DIM + t] * (1.f / N_DIM);
    __syncthreads();
    if (t < R_DIM) {
        float a = fc1b[t];
        for (int c = 0; c < C_DIM; ++c) a += sp[c] * fc1w[t * C_DIM + c];
        sh[t] = a > 0.f ? a : 0.f;
    }
    __syncthreads();
    float a = fc2b[t];
    for (int j = 0; j < R_DIM; ++j) a += sh[j] * fc2w[t * R_DIM + j];
    chw[b * C_DIM + t] = 1.f / (1.f + __builtin_amdgcn_exp2f(-a * 1.44269504089f));
}

// ---- 4: fused QKV projection + SE pooling ----
// Staging: pair-exchange transpose (1 shfl level), u32 LDS writes, swizzle (n>>2)&7.
// All 3 z MFMA'd in one 6-chain loop; all 3 epilogues share ONE barrier pair.
__global__ __launch_bounds__(256) void qkv_kernel(const float* __restrict__ x,
                                                  const u16* __restrict__ w3,
                                                  u16* __restrict__ theta,
                                                  u16* __restrict__ phiT,
                                                  u16* __restrict__ gT,
                                                  float* __restrict__ pooled) {
    const int bid = blockIdx.x;
    const int b = bid & 7, nt = bid >> 3;
    const int n0 = nt * 64;
    const int t = threadIdx.x, lane = t & 63, w = t >> 6;
    const int cl = lane & 31, h = lane >> 5;

    // As [64n][256c] (32KB) overlaid by Ep [128][136] (34KB); EpG [128][72] (18KB)
    __shared__ u16 SMQ[26624];
    u16* As  = SMQ;
    u16* Ep  = SMQ;
    u16* EpG = SMQ + 17408;

    {   // stage x[b, :, n0:n0+64] -> As[n][c] bf16 (transposed); fused SE pooling
        const float* xb = x + ((size_t)b * C_DIM) * N_DIM + n0;
        for (int it = 0; it < 16; ++it) {
            int id = it * 256 + t;
            int c = id >> 4, l16 = id & 15;
            float4 v = *(const float4*)(xb + (size_t)c * N_DIM + l16 * 4);
            float s = (v.x + v.y) + (v.z + v.w);
            s += __shfl_xor(s, 1); s += __shfl_xor(s, 2);
            s += __shfl_xor(s, 4); s += __shfl_xor(s, 8);
            if ((t & 15) == 0) atomicAdd(&pooled[b * C_DIM + c], s);
            u32 lo = pk2t(v.x, v.y), hi = pk2t(v.z, v.w);
            u32 plo = (u32)__shfl_xor((int)lo, 16);
            u32 phi2 = (u32)__shfl_xor((int)hi, 16);
            u32 w0, w1; int nrow, cp;
            if ((c & 1) == 0) {   // rows k=0,1; cols (c, c+1)
                w0 = __builtin_amdgcn_perm(plo, lo, 0x05040100u);
                w1 = __builtin_amdgcn_perm(plo, lo, 0x07060302u);
                nrow = 4 * l16; cp = c;
            } else {              // rows k=2,3; cols (c-1, c)
                w0 = __builtin_amdgcn_perm(hi, phi2, 0x05040100u);
                w1 = __builtin_amdgcn_perm(hi, phi2, 0x07060302u);
                nrow = 4 * l16 + 2; cp = c - 1;
            }
            int base = (((cp >> 3) ^ (l16 & 7)) << 3) + (cp & 7);
            *(u32*)&As[nrow * 256 + base] = w0;
            *(u32*)&As[(nrow + 1) * 256 + base] = w1;
        }
    }
    __syncthreads();

    const int mt = w & 1;    // n-tile
    const int ip = w >> 1;   // i-pair
    bf16x8 afr[16];
    #pragma unroll
    for (int ks = 0; ks < 16; ++ks) {
        int r = mt * 32 + cl;
        int g = 2 * ks + h;
        afr[ks] = *(const bf16x8*)&As[r * 256 + ((g ^ ((r >> 2) & 7)) << 3)];
    }
    __syncthreads();   // all afr loaded -> As reusable as Ep

    // MFMA: 6 independent chains (theta f0/f1, phi f0/f1, g f0/f1)
    f32x16 acc[6] = {};
    const u16* wz0 = w3;
    const u16* wz1 = w3 + 32768;
    const u16* wz2 = w3 + 65536;
    #pragma unroll
    for (int ks = 0; ks < 16; ++ks) {
        bf16x8 a = afr[ks];
        #pragma unroll
        for (int f = 0; f < 2; ++f) {
            size_t off = (size_t)((2 * ip + f) * 32 + cl) * C_DIM + ks * 16 + h * 8;
            acc[f]     = __builtin_amdgcn_mfma_f32_32x32x16_bf16(a, *(const bf16x8*)(wz0 + off), acc[f], 0, 0, 0);
            acc[2 + f] = __builtin_amdgcn_mfma_f32_32x32x16_bf16(a, *(const bf16x8*)(wz1 + off), acc[2 + f], 0, 0, 0);
            acc[4 + f] = __builtin_amdgcn_mfma_f32_32x32x16_bf16(a, *(const bf16x8*)(wz2 + off), acc[4 + f], 0, 0, 0);
        }
    }

    // epilogue LDS writes: theta rows [0,64), phi rows [64,128) in Ep; gT in EpG
    #pragma unroll
    for (int f = 0; f < 2; ++f) {
        int i = (2 * ip + f) * 32 + cl;
        #pragma unroll
        for (int r2 = 0; r2 < 4; ++r2) {
            #pragma unroll
            for (int e = 0; e < 4; ++e) {
                int n = mt * 32 + 8 * r2 + 4 * h + e;
                Ep[n * 136 + i] = f2bf(acc[f][4 * r2 + e] * TH_SCALE);
                Ep[(64 + n) * 136 + i] = f2bf(acc[2 + f][4 * r2 + e]);
            }
            u32 lo = pk2(acc[4 + f][4 * r2 + 0], acc[4 + f][4 * r2 + 1]);
            u32 hi = pk2(acc[4 + f][4 * r2 + 2], acc[4 + f][4 * r2 + 3]);
            int nb = mt * 32 + 8 * r2 + 4 * h;
            *(u32*)&EpG[i * 72 + nb] = lo;
            *(u32*)&EpG[i * 72 + nb + 2] = hi;
        }
    }
    __syncthreads();

    // vector stores: theta/phi (8 iters), gT (4 iters)
    #pragma unroll
    for (int it = 0; it < 8; ++it) {
        int id = it * 256 + t;
        int row = id >> 4, l16 = id & 15;
        f32x4 vv = *(const f32x4*)&Ep[row * 136 + l16 * 8];
        u16* dst = (row < 64) ? theta : phiT;
        int n = row & 63;
        *(f32x4*)(dst + ((size_t)(b * N_DIM) + n0 + n) * I_DIM + l16 * 8) = vv;
    }
    #pragma unroll
    for (int it = 0; it < 4; ++it) {
        int id = it * 256 + t;
        int i = id >> 3, l8 = id & 7;
        f32x4 vv = *(const f32x4*)&EpG[i * 72 + l8 * 8];
        *(f32x4*)(gT + ((size_t)(b * I_DIM) + i) * N_DIM + n0 + l8 * 8) = vv;
    }
}

// ---- 5: flash attention, 32x32 MFMA, q=32/wave, dbuf K/V, in-flight prefetch ----
// R5-proven structure; O written RAW (no normalize) + l partials; oproj rescales.
__global__ __launch_bounds__(256) void attn_kernel(const u16* __restrict__ theta,
                                                   const u16* __restrict__ phiT,
                                                   const u16* __restrict__ gT,
                                                   u16* __restrict__ ao0, u16* __restrict__ ao1,
                                                   float* __restrict__ l0, float* __restrict__ l1) {
    const int bid = blockIdx.x;
    const int b = bid & 7, mh = (bid >> 3) & 1, qt = bid >> 4;
    const int t = threadIdx.x, lane = t & 63, w = t >> 6;
    const int cl = lane & 31, h = lane >> 5;
    const int qw = qt * 128 + w * 32;    // wave q-base

    __shared__ u16 SM[32768];            // 64KB: K0 V0 | K1 V1 (reused for epilogue)

    bf16x8 qf[8];
    {
        const u16* qp = theta + ((size_t)(b * N_DIM) + qw + cl) * I_DIM + h * 8;
        #pragma unroll
        for (int ks = 0; ks < 8; ++ks) qf[ks] = *(const bf16x8*)(qp + ks * 16);
    }

    const u16* kbase = phiT + (size_t)b * N_DIM * I_DIM + (size_t)(mh * 2048) * I_DIM;
    const u16* vbase = gT + (size_t)b * I_DIM * N_DIM + mh * 2048;
    const u16* kptr[4]; const u16* vptr[4];
    #pragma unroll
    for (int it = 0; it < 4; ++it) {
        int gi = (w * 4 + it) * 64 + lane;
        int kr = gi >> 4, kg = gi & 15;
        kptr[it] = kbase + (size_t)kr * I_DIM + ((kg ^ (kr & 7)) << 3);
        int vr = gi >> 3, vg = gi & 7;
        vptr[it] = vbase + (size_t)vr * N_DIM + ((vg ^ (vr & 7)) << 3);
    }

    auto issue = [&](int p) {
        u16* Kd = SM + p * 16384;
        u16* Vd = SM + p * 16384 + 8192;
        #pragma unroll
        for (int it = 0; it < 4; ++it) { async16(kptr[it], Kd + (w * 4 + it) * 512); kptr[it] += 64 * I_DIM; }
        #pragma unroll
        for (int it = 0; it < 4; ++it) { async16(vptr[it], Vd + (w * 4 + it) * 512); vptr[it] += 64; }
    };

    float lsum = 0.f;
    f32x16 O[4] = {};

    issue(0);   // chunk 0 -> buf 0

    for (int mc = 0; mc < 32; ++mc) {
        const int p = mc & 1;
        __asm__ volatile("s_barrier" ::: "memory");
        if (mc < 31) {
            issue(1 - p);   // prefetch; stays in flight across barrier B
            __asm__ volatile("s_waitcnt vmcnt(8)" ::: "memory");
        } else {
            __asm__ volatile("s_waitcnt vmcnt(0)" ::: "memory");
        }
        __asm__ volatile("s_barrier" ::: "memory");

        const u16* Ks = SM + p * 16384;
        const u16* Vs = SM + p * 16384 + 8192;

        // S^T = K Q^T (row=m, col=q); theta pre-scaled so P = exp2(S)
        u32 pk[8][2];
        #pragma unroll
        for (int mt2 = 0; mt2 < 2; ++mt2) {
            f32x16 S = {};
            #pragma unroll
            for (int ks = 0; ks < 8; ++ks) {
                int r = mt2 * 32 + cl;
                bf16x8 kf = *(const bf16x8*)&Ks[r * 128 + (((2 * ks + h) ^ (r & 7)) << 3)];
                S = __builtin_amdgcn_mfma_f32_32x32x16_bf16(kf, qf[ks], S, 0, 0, 0);
            }
            #pragma unroll
            for (int r2 = 0; r2 < 4; ++r2) {
                float p0 = __builtin_amdgcn_exp2f(S[4 * r2 + 0]);
                float p1 = __builtin_amdgcn_exp2f(S[4 * r2 + 1]);
                float p2 = __builtin_amdgcn_exp2f(S[4 * r2 + 2]);
                float p3 = __builtin_amdgcn_exp2f(S[4 * r2 + 3]);
                lsum += (p0 + p1) + (p2 + p3);
                pk[mt2 * 4 + r2][0] = pk2t(p0, p1);
                pk[mt2 * 4 + r2][1] = pk2t(p2, p3);
            }
        }

        // O += P V ; A-frag assembled via shfl_xor(32) exchange (no LDS)
        #pragma unroll
        for (int ks = 0; ks < 4; ++ks) {
            u32 a0 = pk[2 * ks][0], a1 = pk[2 * ks][1];
            u32 b0 = pk[2 * ks + 1][0], b1 = pk[2 * ks + 1][1];
            bool hb = (h != 0);
            u32 own0 = hb ? b0 : a0, own1 = hb ? b1 : a1;
            u32 xf0 = hb ? a0 : b0, xf1 = hb ? a1 : b1;
            u32 rc0 = (u32)__shfl_xor((int)xf0, 32);
            u32 rc1 = (u32)__shfl_xor((int)xf1, 32);
            BF8 A;
            A.u[0] = hb ? rc0 : own0;
            A.u[1] = hb ? rc1 : own1;
            A.u[2] = hb ? own0 : rc0;
            A.u[3] = hb ? own1 : rc1;
            #pragma unroll
            for (int f = 0; f < 4; ++f) {
                int ir = f * 32 + cl;
                bf16x8 vf = *(const bf16x8*)&Vs[ir * 64 + (((2 * ks + h) ^ (ir & 7)) << 3)];
                O[f] = __builtin_amdgcn_mfma_f32_32x32x16_bf16(A.v, vf, O[f], 0, 0, 0);
            }
        }
    }

    // l partial (raw); O written raw — bf16 is scale-invariant, oproj rescales
    lsum += __shfl_xor(lsum, 32);
    u16* aop = (mh == 0) ? ao0 : ao1;
    float* lp = (mh == 0) ? l0 : l1;
    if (h == 0) lp[(size_t)b * N_DIM + qw + cl] = lsum;

    // epilogue staging uses buf0 region (last chunk 31 lives in buf1 — disjoint)
    u16* ep = SM + w * 4096;   // [q32][i128] per wave
    #pragma unroll
    for (int f = 0; f < 4; ++f)
        #pragma unroll
        for (int r2 = 0; r2 < 4; ++r2)
            #pragma unroll
            for (int e = 0; e < 4; ++e) {
                int q = 8 * r2 + 4 * h + e;
                ep[q * 128 + f * 32 + cl] = f2bf(O[f][4 * r2 + e]);
            }
    __asm__ volatile("s_waitcnt lgkmcnt(0)" ::: "memory");
    #pragma unroll
    for (int it = 0; it < 8; ++it) {
        int id = it * 64 + lane;
        int q = id >> 4, l16 = id & 15;
        f32x4 vv = *(const f32x4*)&ep[q * 128 + l16 * 8];
        *(f32x4*)(aop + ((size_t)(b * N_DIM) + qw + q) * I_DIM + l16 * 8) = vv;
    }
}

// ---- 6: out projection + partial combine + BN stats ----
__global__ __launch_bounds__(256) void oproj_kernel(const u16* __restrict__ ao0,
                                                    const u16* __restrict__ ao1,
                                                    const float* __restrict__ l0,
                                                    const float* __restrict__ l1,
                                                    const u16* __restrict__ owb,
                                                    u16* __restrict__ out2,
                                                    float* __restrict__ bnsum,
                                                    float* __restrict__ bnsumsq) {
    const int bid = blockIdx.x;
    const int b = bid & 7, nt = bid >> 3;
    const int n0 = nt * 64;
    const int t = threadIdx.x, lane = t & 63, w = t >> 6;
    const int cl = lane & 31, h = lane >> 5;

    __shared__ u16 Ep[256 * 72];   // [c][n 72pad]
    __shared__ float lsum[C_DIM], lsq[C_DIM];
    lsum[t] = 0.f; lsq[t] = 0.f;
    __syncthreads();

    const int mt = w & 1;
    const int nn = n0 + mt * 32 + cl;
    float inv;
    {
        float la = l0[(size_t)b * N_DIM + nn], lb = l1[(size_t)b * N_DIM + nn];
        inv = 1.f / (la + lb);
    }
    bf16x8 afr[8];
    {
        const u16* p0 = ao0 + ((size_t)(b * N_DIM) + nn) * I_DIM + h * 8;
        const u16* p1 = ao1 + ((size_t)(b * N_DIM) + nn) * I_DIM + h * 8;
        #pragma unroll
        for (int ks = 0; ks < 8; ++ks) {
            bf16x8 x0 = *(const bf16x8*)(p0 + ks * 16);
            bf16x8 x1 = *(const bf16x8*)(p1 + ks * 16);
            const u16* u0 = (const u16*)&x0;
            const u16* u1 = (const u16*)&x1;
            float c0 = (bf2f(u0[0]) + bf2f(u1[0])) * inv;
            float c1 = (bf2f(u0[1]) + bf2f(u1[1])) * inv;
            float c2 = (bf2f(u0[2]) + bf2f(u1[2])) * inv;
            float c3 = (bf2f(u0[3]) + bf2f(u1[3])) * inv;
            float c4 = (bf2f(u0[4]) + bf2f(u1[4])) * inv;
            float c5 = (bf2f(u0[5]) + bf2f(u1[5])) * inv;
            float c6 = (bf2f(u0[6]) + bf2f(u1[6])) * inv;
            float c7 = (bf2f(u0[7]) + bf2f(u1[7])) * inv;
            BF8 r;
            r.u[0] = pk2(c0, c1); r.u[1] = pk2(c2, c3);
            r.u[2] = pk2(c4, c5); r.u[3] = pk2(c6, c7);
            afr[ks] = r.v;
        }
    }

    f32x16 D[4] = {};
    #pragma unroll
    for (int ks = 0; ks < 8; ++ks) {
        #pragma unroll
        for (int j = 0; j < 4; ++j) {
            int cr = ((w >> 1) * 4 + j) * 32 + cl;
            bf16x8 bfr = *(const bf16x8*)(owb + (size_t)cr * I_DIM + ks * 16 + h * 8);
            D[j] = __builtin_amdgcn_mfma_f32_32x32x16_bf16(afr[ks], bfr, D[j], 0, 0, 0);
        }
    }

    #pragma unroll
    for (int j = 0; j < 4; ++j) {
        int c = ((w >> 1) * 4 + j) * 32 + cl;
        float s1 = 0.f, s2 = 0.f;
        #pragma unroll
        for (int r2 = 0; r2 < 4; ++r2) {
            float v0 = D[j][4 * r2 + 0], v1 = D[j][4 * r2 + 1];
            float v2 = D[j][4 * r2 + 2], v3 = D[j][4 * r2 + 3];
            s1 += (v0 + v1) + (v2 + v3);
            s2 += (v0 * v0 + v1 * v1) + (v2 * v2 + v3 * v3);
            int nb = mt * 32 + 8 * r2 + 4 * h;
            *(u32*)&Ep[c * 72 + nb] = pk2(v0, v1);
            *(u32*)&Ep[c * 72 + nb + 2] = pk2(v2, v3);
        }
        atomicAdd(&lsum[c], s1);
        atomicAdd(&lsq[c], s2);
    }
    __syncthreads();
    #pragma unroll
    for (int it = 0; it < 8; ++it) {
        int id = it * 256 + t;
        int c = id >> 3, l8 = id & 7;
        f32x4 vv = *(const f32x4*)&Ep[c * 72 + l8 * 8];
        *(f32x4*)(out2 + ((size_t)(b * C_DIM) + c) * N_DIM + n0 + l8 * 8) = vv;
    }
    atomicAdd(&bnsum[t], lsum[t]);
    atomicAdd(&bnsumsq[t], lsq[t]);
}

// ---- 7: BN normalize + SE scale + residual ----
__global__ void final_kernel(const float* __restrict__ x, const u16* __restrict__ out2,
                             const float* __restrict__ bnsum, const float* __restrict__ bnsumsq,
                             const float* __restrict__ gamma, const float* __restrict__ beta,
                             const float* __restrict__ chw, float* __restrict__ out) {
    int idx = blockIdx.x * 256 + threadIdx.x;
    int e = idx * 4;
    int b = e >> 20;
    int c = (e >> 12) & 255;
    float mean = bnsum[c] * (1.f / 32768.f);
    float var = bnsumsq[c] * (1.f / 32768.f) - mean * mean;
    float sc = gamma[c] * rsqrtf(var + 1e-5f);
    float sh = beta[c] - mean * sc;
    float cw = chw[b * C_DIM + c];
    ushort4 o16 = ((const ushort4*)out2)[idx];
    float4 xv = ((const float4*)x)[idx];
    float4 res;
    res.x = xv.x + (bf2f(o16.x) * sc + sh) * cw;
    res.y = xv.y + (bf2f(o16.y) * sc + sh) * cw;
    res.z = xv.z + (bf2f(o16.z) * sc + sh) * cw;
    res.w = xv.w + (bf2f(o16.w) * sc + sh) * cw;
    ((float4*)out)[idx] = res;
}

extern "C" void kernel_launch(void* const* d_in, const int* in_sizes, int n_in,
                              void* d_out, int out_size, void* d_ws, size_t ws_size,
                              hipStream_t stream) {
    const float* x   = (const float*)d_in[0];
    const float* tw  = (const float*)d_in[1];
    const float* pw  = (const float*)d_in[2];
    const float* gw  = (const float*)d_in[3];
    const float* ow  = (const float*)d_in[4];
    const float* gam = (const float*)d_in[5];
    const float* bet = (const float*)d_in[6];
    const float* f1w = (const float*)d_in[7];
    const float* f1b = (const float*)d_in[8];
    const float* f2w = (const float*)d_in[9];
    const float* f2b = (const float*)d_in[10];
    float* out = (float*)d_out;

    char* ws = (char*)d_ws;
    float* bnsum   = (float*)(ws + OFF_BNSUM);
    float* bnsumsq = (float*)(ws + OFF_BNSQ);
    float* pooled  = (float*)(ws + OFF_POOL);
    float* chw     = (float*)(ws + OFF_CHW);
    u16*   w3      = (u16*)(ws + OFF_W3);
    u16*   owb     = (u16*)(ws + OFF_OWB);
    u16*   ao0     = (u16*)(ws + OFF_AO0);
    u16*   ao1     = (u16*)(ws + OFF_AO1);
    u16*   theta   = (u16*)(ws + OFF_THETA);
    u16*   phiT    = (u16*)(ws + OFF_PHIT);
    u16*   gT      = (u16*)(ws + OFF_GT);
    float* l0      = (float*)(ws + OFF_L0);
    float* l1      = (float*)(ws + OFF_L1);
    u16*   out2    = (u16*)(ws + OFF_OUT2);

    prep_kernel<<<384, 256, 0, stream>>>(tw, pw, gw, ow, w3, owb, bnsum, pooled);
    qkv_kernel<<<512, 256, 0, stream>>>(x, w3, theta, phiT, gT, pooled);
    se_kernel<<<B_DIM, 256, 0, stream>>>(pooled, f1w, f1b, f2w, f2b, chw);
    attn_kernel<<<512, 256, 0, stream>>>(theta, phiT, gT, ao0, ao1, l0, l1);
    oproj_kernel<<<512, 256, 0, stream>>>(ao0, ao1, l0, l1, owb, out2, bnsum, bnsumsq);
    final_kernel<<<8192, 256, 0, stream>>>(x, out2, bnsum, bnsumsq, gam, bet, chw, out);
}